// Round 1
// baseline (814.444 us; speedup 1.0000x reference)
//
#include <hip/hip_runtime.h>
#include <math.h>

#define HIDDEN 4096
#define NEXP   128
#define TOPK   8
#define BT     32   // tokens per block
#define BK     32   // K tile
#define SPAD   129  // padded score row stride (doubles) to avoid bank conflicts

// One block: 32 tokens x 128 experts, fp64 accumulation for exact-rank matching.
__global__ __launch_bounds__(256)
void router_kernel(const float* __restrict__ X,
                   const float* __restrict__ W,
                   const float* __restrict__ Bias,
                   float* __restrict__ Out,
                   int T)
{
    // 40 KB of doubles, reused for the epilogue score matrix (32 x SPAD = 4128 <= 5120)
    __shared__ double smem[BK * BT + BK * NEXP];
    double* Xs = smem;             // [BK][BT]   k-major, token minor
    double* Ws = smem + BK * BT;   // [BK][NEXP] k-major, expert minor

    const int tid = threadIdx.x;
    const int tokBase = blockIdx.x * BT;
    if (tokBase >= T) return;

    // staging assignments
    const int xr = tid >> 3;            // 0..31 : token row for X stage
    const int xc = (tid & 7) * 4;       // col group (4 floats)
    const int we = tid >> 1;            // 0..127 : expert row for W stage
    const int wc = (tid & 1) * 16;      // col base (16 floats)

    // compute assignments: 4 tokens x 4 experts per thread
    const int t0 = (tid & 7) * 4;       // token offset in tile
    const int e0 = (tid >> 3) * 4;      // expert offset

    double acc[4][4];
    #pragma unroll
    for (int i = 0; i < 4; i++)
        #pragma unroll
        for (int j = 0; j < 4; j++)
            acc[i][j] = 0.0;

    const float* xbase = X + (size_t)(tokBase + xr) * HIDDEN + xc;
    const float* wbase = W + (size_t)we * HIDDEN + wc;

    for (int k0 = 0; k0 < HIDDEN; k0 += BK) {
        // ---- stage X tile (32x32 floats -> f64, transposed to [k][token]) ----
        {
            const float4 xv = *(const float4*)(xbase + k0);
            Xs[(xc + 0) * BT + xr] = (double)xv.x;
            Xs[(xc + 1) * BT + xr] = (double)xv.y;
            Xs[(xc + 2) * BT + xr] = (double)xv.z;
            Xs[(xc + 3) * BT + xr] = (double)xv.w;
        }
        // ---- stage W tile (128x32 floats -> f64, [k][expert]) ----
        #pragma unroll
        for (int j = 0; j < 4; j++) {
            const float4 wv = *(const float4*)(wbase + k0 + 4 * j);
            const int kk = wc + 4 * j;
            Ws[(kk + 0) * NEXP + we] = (double)wv.x;
            Ws[(kk + 1) * NEXP + we] = (double)wv.y;
            Ws[(kk + 2) * NEXP + we] = (double)wv.z;
            Ws[(kk + 3) * NEXP + we] = (double)wv.w;
        }
        __syncthreads();

        // ---- inner product: 16 f64 FMAs per k ----
        #pragma unroll 4
        for (int k = 0; k < BK; k++) {
            const double* xrow = Xs + k * BT + t0;
            const double* wrow = Ws + k * NEXP + e0;
            const double x0 = xrow[0], x1 = xrow[1], x2 = xrow[2], x3 = xrow[3];
            const double w0 = wrow[0], w1 = wrow[1], w2 = wrow[2], w3 = wrow[3];
            acc[0][0] = fma(x0, w0, acc[0][0]);
            acc[0][1] = fma(x0, w1, acc[0][1]);
            acc[0][2] = fma(x0, w2, acc[0][2]);
            acc[0][3] = fma(x0, w3, acc[0][3]);
            acc[1][0] = fma(x1, w0, acc[1][0]);
            acc[1][1] = fma(x1, w1, acc[1][1]);
            acc[1][2] = fma(x1, w2, acc[1][2]);
            acc[1][3] = fma(x1, w3, acc[1][3]);
            acc[2][0] = fma(x2, w0, acc[2][0]);
            acc[2][1] = fma(x2, w1, acc[2][1]);
            acc[2][2] = fma(x2, w2, acc[2][2]);
            acc[2][3] = fma(x2, w3, acc[2][3]);
            acc[3][0] = fma(x3, w0, acc[3][0]);
            acc[3][1] = fma(x3, w1, acc[3][1]);
            acc[3][2] = fma(x3, w2, acc[3][2]);
            acc[3][3] = fma(x3, w3, acc[3][3]);
        }
        __syncthreads();
    }

    // ---- epilogue: scores (sigmoid + bias) into padded LDS ----
    double* S = smem;  // [BT][SPAD], overlaps Xs/Ws (safe: barrier above ended all reads)
    #pragma unroll
    for (int i = 0; i < 4; i++) {
        #pragma unroll
        for (int j = 0; j < 4; j++) {
            const double l = acc[i][j];
            const double s = 1.0 / (1.0 + exp(-l)) + (double)Bias[e0 + j];
            S[(t0 + i) * SPAD + (e0 + j)] = s;
        }
    }
    __syncthreads();

    // ---- top-8 selection, one thread per token (stable: lowest index on ties) ----
    if (tid < BT) {
        double* row = S + tid * SPAD;
        int    cidx[TOPK];
        double csc[TOPK];
        #pragma unroll
        for (int p = 0; p < TOPK; p++) {
            double best = -1e300;
            int bi = 0;
            for (int e = 0; e < NEXP; e++) {
                const double v = row[e];
                if (v > best) { best = v; bi = e; }
            }
            cidx[p] = bi;
            csc[p]  = best;
            row[bi] = -1e300;
        }
        double sum = 0.0;
        double wts[TOPK];
        #pragma unroll
        for (int p = 0; p < TOPK; p++) {
            const double sg = csc[p] - (double)Bias[cidx[p]];  // un-biased sigmoid score
            wts[p] = sg;
            sum += sg;
        }
        const double inv = 1.0 / (sum + 1e-20);
        const int tok = tokBase + tid;
        float* oi = Out + (size_t)tok * TOPK;
        float* ow = Out + (size_t)T * TOPK + (size_t)tok * TOPK;
        #pragma unroll
        for (int p = 0; p < TOPK; p++) {
            oi[p] = (float)cidx[p];
            ow[p] = (float)(wts[p] * inv);
        }
    }
}

extern "C" void kernel_launch(void* const* d_in, const int* in_sizes, int n_in,
                              void* d_out, int out_size, void* d_ws, size_t ws_size,
                              hipStream_t stream) {
    const float* X    = (const float*)d_in[0];
    const float* W    = (const float*)d_in[1];
    const float* Bias = (const float*)d_in[2];
    float* Out = (float*)d_out;
    const int T = in_sizes[0] / HIDDEN;

    dim3 grid((T + BT - 1) / BT);
    dim3 block(256);
    hipLaunchKernelGGL(router_kernel, grid, block, 0, stream, X, W, Bias, Out, T);
}